// Round 4
// baseline (3805.532 us; speedup 1.0000x reference)
//
#include <hip/hip_runtime.h>

#define WAVE 64

// ---------------------------------------------------------------------------
// split pointcloud (B,N,6) -> xyz (B,N,3) + feats (B,N,3)
__global__ __launch_bounds__(256) void split_kernel(const float* __restrict__ pc,
    float* __restrict__ xyz, float* __restrict__ feats, int total) {
  int t = blockIdx.x * blockDim.x + threadIdx.x;
  if (t >= total) return;
  const float* p = pc + (size_t)t * 6;
  xyz[t * 3 + 0] = p[0]; xyz[t * 3 + 1] = p[1]; xyz[t * 3 + 2] = p[2];
  feats[t * 3 + 0] = p[3]; feats[t * 3 + 1] = p[4]; feats[t * 3 + 2] = p[5];
}

__global__ __launch_bounds__(256) void zero_kernel(float* __restrict__ p, int n) {
  int t = blockIdx.x * blockDim.x + threadIdx.x;
  if (t < n) p[t] = 0.f;
}

// ---------------------------------------------------------------------------
// Fused 64-bit wave max via DPP (rocPRIM row_shr 1/2/4/8 + row_bcast15/31).
// Both halves shuffled with the same ctrl => neighbor's full 64-bit key; with
// old=v, invalid source lanes yield max(v,v)=v. Full max lands in lane 63.
__device__ __forceinline__ unsigned long long dpp_max_u64(unsigned long long v) {
#define DPP_STEP_U64(ctrl) { \
    unsigned lo_ = (unsigned)v, hi_ = (unsigned)(v >> 32); \
    unsigned tlo_ = (unsigned)__builtin_amdgcn_update_dpp((int)lo_, (int)lo_, ctrl, 0xf, 0xf, false); \
    unsigned thi_ = (unsigned)__builtin_amdgcn_update_dpp((int)hi_, (int)hi_, ctrl, 0xf, 0xf, false); \
    unsigned long long t_ = ((unsigned long long)thi_ << 32) | tlo_; \
    if (t_ > v) v = t_; }
  DPP_STEP_U64(0x111) DPP_STEP_U64(0x112) DPP_STEP_U64(0x114)
  DPP_STEP_U64(0x118) DPP_STEP_U64(0x142) DPP_STEP_U64(0x143)
#undef DPP_STEP_U64
  return v;  // valid in lane 63
}

// ---------------------------------------------------------------------------
// FPS, layer 0 — barrier-free multi-wave combine (round-4 redesign).
// Round-3 evidence: poll mechanism (RMW vs load) irrelevant — per-iter 3430cy
// was (a) a COLD slot line every iteration (it-indexed slots), (b) 16-wave
// LDS atomicMax + 2 barriers intra-WG, (c) winner re-broadcast + coord fetch.
// New structure: 32 independent waves per batch (8 WGs x 4 waves, 8 pts/lane,
// ZERO LDS, ZERO barriers). Per iteration each wave:
//   1. computes its local best key = dist32<<32 | tag18<<14 | (16383-idx)14
//      (tag = it; freshness check => slots REUSED: 2 parity lines per batch,
//       permanently LLC-hot)
//   2. DPP-reduces the wave (one fused u64 chain), lane 63 atomicExch's the
//      wave's slot on line[it&1] (fire-and-forget)
//   3. lanes 0..31 poll the 32 slots until tag==it, one more DPP u64 max +
//      readlane(63) broadcasts the winner to all lanes
// Laggard bound: publishing it+2 (overwrites parity of it) requires polling
// ALL 32 slots fresh at it+1, which requires every wave past it => no
// overwrite-before-read. Tag mismatch on stale (it-2) values is guaranteed.
// Timeout (~20ms) substitutes a losing tagged key: a protocol bug becomes a
// wrong answer, never a hang. Ordering on (dist, inv_idx) within an iteration
// is unchanged -> pick sequence bit-identical to the verified kernel.
#define FPS_WPB  32    // waves per batch
#define FPS_PPL  8     // points per lane (32*64*8 = 16384)
__global__ __launch_bounds__(256) void fps_big_multi_kernel(
    const float* __restrict__ xyz, float* __restrict__ new_xyz,
    unsigned long long* __restrict__ gkey, int N, int S) {
  const int b = blockIdx.x & 7;
  const int w = blockIdx.x >> 3;          // WG within batch, 0..7
  const int tid = threadIdx.x;
  const int lane = tid & 63;
  const int gw = w * 4 + (tid >> 6);      // wave within batch, 0..31
  const float* px = xyz + (size_t)b * N * 3;
  const int base = gw * (FPS_PPL * 64);   // this wave's point range
  unsigned long long* slots = gkey + (size_t)b * (2 * FPS_WPB);
  float rx[FPS_PPL], ry[FPS_PPL], rz[FPS_PPL], mind[FPS_PPL];
#pragma unroll
  for (int p = 0; p < FPS_PPL; ++p) {
    int i = base + p * 64 + lane;
    rx[p] = px[i * 3 + 0]; ry[p] = px[i * 3 + 1]; rz[p] = px[i * 3 + 2];
    asm volatile("" : "+v"(rx[p]), "+v"(ry[p]), "+v"(rz[p]));
    mind[p] = 1e10f;
  }
  float qx = px[0], qy = px[1], qz = px[2];   // pick 0 is always index 0
  if (blockIdx.x < 8 && tid == 0) {           // w==0
    float* o = new_xyz + (size_t)b * S * 3;
    o[0] = qx; o[1] = qy; o[2] = qz;
  }
  for (unsigned it = 1; it < (unsigned)S; ++it) {
    float bestv = -1.f; unsigned besti = 0;
#pragma unroll
    for (int p = 0; p < FPS_PPL; ++p) {
      float dx = __fsub_rn(rx[p], qx);
      float dy = __fsub_rn(ry[p], qy);
      float dz = __fsub_rn(rz[p], qz);
      float d = __fadd_rn(__fadd_rn(__fmul_rn(dx, dx), __fmul_rn(dy, dy)), __fmul_rn(dz, dz));
      float mo = fminf(mind[p], d);
      mind[p] = mo;
      // p ascending => index ascending within thread: keeps first max on ties
      if (mo > bestv) { bestv = mo; besti = (unsigned)(base + p * 64 + lane); }
    }
    unsigned long long key = ((unsigned long long)__float_as_uint(bestv) << 32)
                           | ((unsigned long long)it << 14)
                           | (unsigned long long)(16383u - besti);
    key = dpp_max_u64(key);
    unsigned long long* line = slots + (size_t)(it & 1u) * FPS_WPB;
    if (lane == 63) {
      // publish this wave's winner; result unused -> fire-and-forget atomic
      atomicExch(&line[gw], key);
    }
    unsigned long long k = 0ull;
    if (lane < FPS_WPB) {
      unsigned long long* sl = &line[lane];
      unsigned long long t0 = __builtin_amdgcn_s_memrealtime();
      int r = 0;
      for (;;) {
        k = __hip_atomic_load(sl, __ATOMIC_RELAXED, __HIP_MEMORY_SCOPE_AGENT);
        if (((k >> 14) & 0x3FFFFull) == (unsigned long long)it) break;
        if ((++r & 63) == 0 &&
            __builtin_amdgcn_s_memrealtime() - t0 > 2000000ull) {
          k = ((unsigned long long)it << 14);   // dist 0: loses to any real key
          break;
        }
      }
    }
    k = dpp_max_u64(k);                          // lanes 32-63 contribute 0
    unsigned klo = (unsigned)__builtin_amdgcn_readlane((int)(unsigned)k, 63);
    unsigned khi = (unsigned)__builtin_amdgcn_readlane((int)(unsigned)(k >> 32), 63);
    int last = (int)(16383u - (khi ? (klo & 0x3FFFu) : (klo & 0x3FFFu)));
    const float* q = px + (size_t)last * 3;      // broadcast L2 load
    qx = q[0]; qy = q[1]; qz = q[2];
    if (blockIdx.x < 8 && tid == 0) {
      float* o = new_xyz + ((size_t)b * S + it) * 3;
      o[0] = qx; o[1] = qy; o[2] = qz;
    }
  }
}

// ---------------------------------------------------------------------------
// FPS, layers 1-3: T=N<=1024, one point per thread (regs) + coords mirrored
// in LDS for the winner lookup (no global reads in the loop). Fused 64-bit
// reduce. (Unchanged from round 3 — verified.)
__global__ void fps_small_kernel(const float* __restrict__ xyz,
    float* __restrict__ new_xyz, int N, int S) {
  const int b = blockIdx.x;
  const int tid = threadIdx.x;
  const int lane = tid & 63;
  const float* px = xyz + (size_t)b * N * 3;
  __shared__ float sx[1024], sy[1024], sz[1024];
  __shared__ unsigned long long s_key[3];
  float x = px[tid * 3 + 0], y = px[tid * 3 + 1], z = px[tid * 3 + 2];
  sx[tid] = x; sy[tid] = y; sz[tid] = z;
  if (tid < 3) s_key[tid] = 0ull;
  float mind = 1e10f;
  float qx = px[0], qy = px[1], qz = px[2];
  if (tid == 0) {
    float* o = new_xyz + (size_t)b * S * 3;
    o[0] = qx; o[1] = qy; o[2] = qz;
  }
  __syncthreads();
  for (unsigned it = 1; it < (unsigned)S; ++it) {
    float dx = __fsub_rn(x, qx);
    float dy = __fsub_rn(y, qy);
    float dz = __fsub_rn(z, qz);
    float d = __fadd_rn(__fadd_rn(__fmul_rn(dx, dx), __fmul_rn(dy, dy)), __fmul_rn(dz, dz));
    mind = fminf(mind, d);
    unsigned long long key = ((unsigned long long)__float_as_uint(mind) << 32)
                           | (0xFFFFFFFFu - (unsigned)tid);
    key = dpp_max_u64(key);
    if (lane == 63) atomicMax(&s_key[it % 3u], key);
    if (tid == 0) s_key[(it + 1) % 3u] = 0ull;
    __syncthreads();
    unsigned long long k = s_key[it % 3u];
    int last = (int)(0xFFFFFFFFu - (unsigned)k);
    qx = sx[last]; qy = sy[last]; qz = sz[last];   // LDS broadcast
    if (tid == 0) {
      float* o = new_xyz + ((size_t)b * S + it) * 3;
      o[0] = qx; o[1] = qy; o[2] = qz;
    }
  }
}

// ---------------------------------------------------------------------------
// Ball query: one wave per center; take the FIRST nsample indices (ascending)
// with d2 < r2 (== nsample smallest indices, matching top_k(-key)). Pad with
// the first hit (0 if no hits).
__global__ __launch_bounds__(256) void ballquery_kernel(const float* __restrict__ xyz,
    const float* __restrict__ centers, int* __restrict__ out_idx,
    int N, int S, int nsample, float r2) {
  int gw = (blockIdx.x * blockDim.x + threadIdx.x) >> 6;
  int lane = threadIdx.x & 63;
  int b = gw / S;
  int s = gw - b * S;
  const float* px = xyz + (size_t)b * N * 3;
  const float* cp = centers + ((size_t)b * S + s) * 3;
  float cx = cp[0], cy = cp[1], cz = cp[2];
  int* out = out_idx + ((size_t)b * S + s) * nsample;
  int cnt = 0;
  int firsti = 0;
  for (int base = 0; base < N; base += WAVE) {
    int i = base + lane;
    float dx = __fsub_rn(cx, px[i * 3 + 0]);
    float dy = __fsub_rn(cy, px[i * 3 + 1]);
    float dz = __fsub_rn(cz, px[i * 3 + 2]);
    float d = __fadd_rn(__fadd_rn(__fmul_rn(dx, dx), __fmul_rn(dy, dy)), __fmul_rn(dz, dz));
    bool hit = d < r2;
    unsigned long long m = __ballot(hit);
    if (hit) {
      int slot = cnt + __popcll(m & ((1ull << lane) - 1ull));
      if (slot < nsample) out[slot] = i;
    }
    if (cnt == 0 && m) firsti = base + __ffsll((unsigned long long)m) - 1;
    cnt += __popcll(m);
    if (cnt >= nsample) break;
  }
  for (int q = cnt + lane; q < nsample; q += WAVE) out[q] = firsti;
}

// ---------------------------------------------------------------------------
// Build X0 rows: [xyz[j]-center (3), feats[j] (ci)] for r=(b,s,k), c in [0,3+ci)
__global__ __launch_bounds__(256) void group_kernel(const float* __restrict__ xyz,
    const float* __restrict__ feats, const float* __restrict__ centers,
    const int* __restrict__ idx, float* __restrict__ X,
    int N, int S, int K, int ci, int R) {
  int t = blockIdx.x * blockDim.x + threadIdx.x;
  int C0 = ci + 3;
  int r = t / C0;
  if (r >= R) return;
  int c = t - r * C0;
  int g = r / K;          // b*S + s
  int b = g / S;
  int j = idx[r];
  float v;
  if (c < 3) v = __fsub_rn(xyz[((size_t)b * N + j) * 3 + c], centers[(size_t)g * 3 + c]);
  else       v = feats[((size_t)b * N + j) * ci + (c - 3)];
  X[(size_t)r * C0 + c] = v;
}

// ---------------------------------------------------------------------------
// Fused tiled f32 GEMM: Y(RxCo) = normReLU(A)(RxC) @ W(CxCo).
//  - if st_in != nullptr, A is normalized elementwise during LDS staging:
//      v = relu(gamma_in[c]*((a - mu[c])*rs[c]) + beta_in[c])
//    with mu/rs from st_in (prev sub-layer's sums; complete by stream order).
//  - per-channel sum/sumsq of Y accumulated into st_out (epilogue atomics)
//    -> replaces the separate stats pass (round-4 fusion).
// R % 64 == 0 always; C/Co guarded.
#define BM 64
#define BN 64
#define BK 16
__global__ __launch_bounds__(256) void mm_fused_kernel(const float* __restrict__ A,
    const float* __restrict__ W, float* __restrict__ Y,
    float* __restrict__ st_out, const float* __restrict__ st_in,
    const float* __restrict__ g_in, const float* __restrict__ b_in,
    int R, int C, int Co, float inv_n) {
  __shared__ float As[BK][BM + 4];
  __shared__ float Bs[BK][BN + 4];
  __shared__ float s_mu[260], s_rs[260], s_g[260], s_b[260];
  __shared__ float s_sum[BN], s_sq[BN];
  int r0 = blockIdx.x * BM;
  int n0 = blockIdx.y * BN;
  int tid = threadIdx.x;
  int tx = tid & 15, ty = tid >> 4;
  if (st_in) {
    for (int c = tid; c < C; c += 256) {
      float mu = st_in[c] * inv_n;
      float var = st_in[512 + c] * inv_n - mu * mu;
      s_mu[c] = mu; s_rs[c] = rsqrtf(var + 1e-5f);
      s_g[c] = g_in[c]; s_b[c] = b_in[c];
    }
  }
  if (tid < BN) { s_sum[tid] = 0.f; s_sq[tid] = 0.f; }
  __syncthreads();
  float acc[4][4] = {};
  for (int k0 = 0; k0 < C; k0 += BK) {
#pragma unroll
    for (int u = 0; u < 4; ++u) {
      int lin = tid + u * 256;
      int row = lin >> 4;
      int cc = lin & 15;
      int c = k0 + cc;
      float v = 0.f;
      if (c < C) {
        v = A[(size_t)(r0 + row) * C + c];
        if (st_in) {
          v = s_g[c] * ((v - s_mu[c]) * s_rs[c]) + s_b[c];
          v = v > 0.f ? v : 0.f;
        }
      }
      As[cc][row] = v;
    }
#pragma unroll
    for (int u = 0; u < 4; ++u) {
      int lin = tid + u * 256;
      int kk = lin >> 6;
      int n = lin & 63;
      int c = k0 + kk;
      Bs[kk][n] = (c < C && (n0 + n) < Co) ? W[(size_t)c * Co + n0 + n] : 0.f;
    }
    __syncthreads();
#pragma unroll
    for (int kk = 0; kk < BK; ++kk) {
      float a0[4], b0[4];
#pragma unroll
      for (int i = 0; i < 4; ++i) a0[i] = As[kk][ty * 4 + i];
#pragma unroll
      for (int jj = 0; jj < 4; ++jj) b0[jj] = Bs[kk][tx * 4 + jj];
#pragma unroll
      for (int i = 0; i < 4; ++i)
#pragma unroll
        for (int jj = 0; jj < 4; ++jj)
          acc[i][jj] = fmaf(a0[i], b0[jj], acc[i][jj]);
    }
    __syncthreads();
  }
#pragma unroll
  for (int i = 0; i < 4; ++i) {
    int r = r0 + ty * 4 + i;
#pragma unroll
    for (int jj = 0; jj < 4; ++jj) {
      int n = n0 + tx * 4 + jj;
      if (n < Co) Y[(size_t)r * Co + n] = acc[i][jj];
    }
  }
  // epilogue: per-column sum/sumsq of this block's tile -> LDS -> global
#pragma unroll
  for (int jj = 0; jj < 4; ++jj) {
    float cs = 0.f, cq = 0.f;
#pragma unroll
    for (int i = 0; i < 4; ++i) { float v = acc[i][jj]; cs += v; cq += v * v; }
    atomicAdd(&s_sum[tx * 4 + jj], cs);
    atomicAdd(&s_sq[tx * 4 + jj], cq);
  }
  __syncthreads();
  if (tid < BN) {
    int n = n0 + tid;
    if (n < Co) {
      atomicAdd(&st_out[n], s_sum[tid]);
      atomicAdd(&st_out[512 + n], s_sq[tid]);
    }
  }
}

// Last sub-layer: normalize+relu then max over the K samples of each group.
__global__ __launch_bounds__(256) void norm_relu_max_kernel(const float* __restrict__ Y,
    float* __restrict__ O, const float* __restrict__ st,
    const float* __restrict__ gamma, const float* __restrict__ beta,
    int G, int K, int Co, float inv_n) {
  int t = blockIdx.x * blockDim.x + threadIdx.x;
  if (t >= G * Co) return;
  int c = t & (Co - 1);
  int g = t / Co;
  float mu = st[c] * inv_n;
  float var = st[512 + c] * inv_n - mu * mu;
  float rs = rsqrtf(var + 1e-5f);
  float ga = gamma[c], be = beta[c];
  const float* yp = Y + (size_t)g * K * Co + c;
  float m = -1e30f;
  for (int k = 0; k < K; ++k) {
    float v = ga * ((yp[(size_t)k * Co] - mu) * rs) + be;
    m = fmaxf(m, v);
  }
  O[t] = m > 0.f ? m : 0.f;
}

// ---------------------------------------------------------------------------
extern "C" void kernel_launch(void* const* d_in, const int* in_sizes, int n_in,
                              void* d_out, int out_size, void* d_ws, size_t ws_size,
                              hipStream_t stream) {
  const float* pc = (const float*)d_in[0];
  float* out = (float*)d_out;
  char* wsb = (char*)d_ws;

  // ws layout: [0,1MB) ball idx; [1MB,+48KB) stats; [2MB,+4KB) fps slots;
  //            [3MB,37MB) bufA; [37MB,104MB) bufB
  int* ballidx = (int*)wsb;
  float* stats = (float*)(wsb + ((size_t)1 << 20));
  unsigned long long* gkey = (unsigned long long*)(wsb + ((size_t)2 << 20));
  float* bufA = (float*)(wsb + ((size_t)3 << 20));
  float* bufB = (float*)(wsb + ((size_t)37 << 20));

  const int B = 8;
  static const int Ns[4] = {16384, 1024, 256, 64};
  static const int Ss[4] = {1024, 256, 64, 16};
  static const int Ks[4] = {32, 32, 16, 16};
  static const double Rr[4] = {0.02, 0.04, 0.06, 0.08};
  static const int Ci[4] = {3, 64, 128, 256};
  static const int mlp[4][4] = {{6,32,32,64},{67,64,64,128},{131,128,128,256},{259,256,256,512}};
  static const size_t ox[5] = {0, 393216, 417792, 423936, 425472};
  static const size_t of[5] = {425856, 819072, 1343360, 1605504, 1736576};

  split_kernel<<<(B * 16384 + 255) / 256, 256, 0, stream>>>(pc, out + ox[0], out + of[0], B * 16384);
  // zero stats (48KB @ +1MB) and fps slots (4KB @ +2MB) in one pass over [1MB,3MB)
  zero_kernel<<<(524288 + 255) / 256, 256, 0, stream>>>(stats, 524288);

  for (int l = 0; l < 4; ++l) {
    const float* xyz = out + ox[l];
    const float* fts = out + of[l];
    float* nxyz = out + ox[l + 1];
    const int N = Ns[l], S = Ss[l], K = Ks[l], ci = Ci[l], C0 = ci + 3;
    const float r2 = (float)(Rr[l] * Rr[l]);

    if (l == 0) fps_big_multi_kernel<<<B * 8, 256, 0, stream>>>(xyz, nxyz, gkey, N, S);
    else        fps_small_kernel<<<B, N, 0, stream>>>(xyz, nxyz, N, S);

    ballquery_kernel<<<(B * S) / 4, 256, 0, stream>>>(xyz, nxyz, ballidx, N, S, K, r2);

    const int R = B * S * K;
    {
      int total = R * C0;
      group_kernel<<<(total + 255) / 256, 256, 0, stream>>>(xyz, fts, nxyz, ballidx, bufA,
                                                            N, S, K, ci, R);
    }

    const float inv_n = 1.0f / (float)R;
    float* X = bufA; float* Y = bufB;
    const float* prev_st = nullptr;
    const float* prev_g = nullptr;
    const float* prev_b = nullptr;
    for (int j = 0; j < 3; ++j) {
      const int cin = mlp[l][j], cout = mlp[l][j + 1];
      const float* Wt = (const float*)d_in[1 + (l * 3 + j) * 3 + 0];
      const float* Ga = (const float*)d_in[1 + (l * 3 + j) * 3 + 1];
      const float* Be = (const float*)d_in[1 + (l * 3 + j) * 3 + 2];
      float* st = stats + (size_t)(l * 3 + j) * 1024;
      dim3 grid(R / 64, (cout + 63) / 64);
      mm_fused_kernel<<<grid, 256, 0, stream>>>(X, Wt, Y, st, prev_st, prev_g, prev_b,
                                                R, cin, cout, inv_n);
      if (j < 2) {
        prev_st = st; prev_g = Ga; prev_b = Be;
        float* tswap = X; X = Y; Y = tswap;
      } else {
        int G = B * S;
        int tot = G * cout;
        norm_relu_max_kernel<<<(tot + 255) / 256, 256, 0, stream>>>(Y, out + of[l + 1], st, Ga, Be,
                                                                    G, K, cout, inv_n);
      }
    }
  }
}

// Round 5
// 2382.098 us; speedup vs baseline: 1.5976x; 1.5976x over previous
//
#include <hip/hip_runtime.h>

#define WAVE 64

// ---------------------------------------------------------------------------
// split pointcloud (B,N,6) -> xyz (B,N,3) + feats (B,N,3)
__global__ __launch_bounds__(256) void split_kernel(const float* __restrict__ pc,
    float* __restrict__ xyz, float* __restrict__ feats, int total) {
  int t = blockIdx.x * blockDim.x + threadIdx.x;
  if (t >= total) return;
  const float* p = pc + (size_t)t * 6;
  xyz[t * 3 + 0] = p[0]; xyz[t * 3 + 1] = p[1]; xyz[t * 3 + 2] = p[2];
  feats[t * 3 + 0] = p[3]; feats[t * 3 + 1] = p[4]; feats[t * 3 + 2] = p[5];
}

__global__ __launch_bounds__(256) void zero_kernel(float* __restrict__ p, int n) {
  int t = blockIdx.x * blockDim.x + threadIdx.x;
  if (t < n) p[t] = 0.f;
}

// ---------------------------------------------------------------------------
// Fused 64-bit wave max via DPP (rocPRIM row_shr 1/2/4/8 + row_bcast15/31).
// Both halves shuffled with the same ctrl => neighbor's full 64-bit key; with
// old=v, invalid source lanes yield max(v,v)=v. Full max lands in lane 63.
__device__ __forceinline__ unsigned long long dpp_max_u64(unsigned long long v) {
#define DPP_STEP_U64(ctrl) { \
    unsigned lo_ = (unsigned)v, hi_ = (unsigned)(v >> 32); \
    unsigned tlo_ = (unsigned)__builtin_amdgcn_update_dpp((int)lo_, (int)lo_, ctrl, 0xf, 0xf, false); \
    unsigned thi_ = (unsigned)__builtin_amdgcn_update_dpp((int)hi_, (int)hi_, ctrl, 0xf, 0xf, false); \
    unsigned long long t_ = ((unsigned long long)thi_ << 32) | tlo_; \
    if (t_ > v) v = t_; }
  DPP_STEP_U64(0x111) DPP_STEP_U64(0x112) DPP_STEP_U64(0x114)
  DPP_STEP_U64(0x118) DPP_STEP_U64(0x142) DPP_STEP_U64(0x143)
#undef DPP_STEP_U64
  return v;  // valid in lane 63
}

// ---------------------------------------------------------------------------
// FPS, layer 0 — round-5: round-2's verified global protocol (it-indexed
// write-once slots, 8 publishers, wave-0 polls with load + RMW fallback +
// timeout) + a LEAN intra-WG stage. Round-4 lesson: 32 publishers + 256
// polling waves saturate the coherent path (6550cy/iter, FETCH 6MB) — keep
// 8 publishers / 8 poller-waves. Round-2 breakdown: ~800-1000cy/iter was the
// 16-wave LDS-atomicMax + 3-slot rotation + 1024-thread barriers. This round:
// WG = 256 threads (4 waves, 8 pts/thread => same per-SIMD compute issue),
// intra-WG combine = DPP per wave -> plain store s_cand[4] -> barrier ->
// wave 0 width-4 shuffle max -> lane 0 publishes. Key lattice unchanged:
//   key = dist32<<32 | (0xFFFFFFFF - idx)   (always nonzero, min-idx ties)
// -> pick sequence bit-identical to the verified kernels.
#define FPS_W   8
#define FPS_PT  8      // points per thread (2048 per WG / 256 threads)
__global__ __launch_bounds__(256, 4) void fps_big_multi_kernel(
    const float* __restrict__ xyz, float* __restrict__ new_xyz,
    unsigned long long* __restrict__ gkey, int N, int S) {
  const int b = blockIdx.x & 7;           // same-XCD heuristic for a batch
  const int w = blockIdx.x >> 3;          // WG within batch, 0..7
  const int tid = threadIdx.x;
  const int lane = tid & 63;
  const int wv = tid >> 6;                // wave within WG, 0..3
  const float* px = xyz + (size_t)b * N * 3;
  const int base = w * (FPS_PT * 256);
  __shared__ unsigned long long s_cand[4];
  __shared__ unsigned long long s_win;
  float rx[FPS_PT], ry[FPS_PT], rz[FPS_PT], mind[FPS_PT];
#pragma unroll
  for (int p = 0; p < FPS_PT; ++p) {
    int i = base + p * 256 + tid;
    rx[p] = px[i * 3 + 0]; ry[p] = px[i * 3 + 1]; rz[p] = px[i * 3 + 2];
    asm volatile("" : "+v"(rx[p]), "+v"(ry[p]), "+v"(rz[p]));
    mind[p] = 1e10f;
  }
  float qx = px[0], qy = px[1], qz = px[2];   // pick 0 is always index 0
  if (w == 0 && tid == 0) {
    float* o = new_xyz + (size_t)b * S * 3;
    o[0] = qx; o[1] = qy; o[2] = qz;
  }
  unsigned long long* slots = gkey + (size_t)b * S * FPS_W;
  for (unsigned it = 1; it < (unsigned)S; ++it) {
    float bestv = -1.f; unsigned besti = 0;
#pragma unroll
    for (int p = 0; p < FPS_PT; ++p) {
      float dx = __fsub_rn(rx[p], qx);
      float dy = __fsub_rn(ry[p], qy);
      float dz = __fsub_rn(rz[p], qz);
      float d = __fadd_rn(__fadd_rn(__fmul_rn(dx, dx), __fmul_rn(dy, dy)), __fmul_rn(dz, dz));
      float mo = fminf(mind[p], d);
      mind[p] = mo;
      // p ascending => index ascending within thread: keeps first max on ties
      if (mo > bestv) { bestv = mo; besti = (unsigned)(base + p * 256 + tid); }
    }
    unsigned long long key = ((unsigned long long)__float_as_uint(bestv) << 32)
                           | (0xFFFFFFFFu - besti);
    key = dpp_max_u64(key);
    if (lane == 63) s_cand[wv] = key;       // plain LDS store, one per wave
    __syncthreads();
    if (tid < 64) {
      unsigned long long k = s_cand[lane & 3];
#pragma unroll
      for (int off = 1; off < 4; off <<= 1) {   // every lane -> WG winner
        unsigned long long o = __shfl_xor(k, off, 4);
        if (o > k) k = o;
      }
      if (lane == 0) {
        // publish this WG's winner (nonzero); fire-and-forget atomic
        atomicExch(&slots[(size_t)it * FPS_W + w], k);
      }
      unsigned long long kk = 0ull;
      if (lane < FPS_W) {
        unsigned long long* sl = &slots[(size_t)it * FPS_W + lane];
        unsigned long long t0 = __builtin_amdgcn_s_memrealtime();
        int r = 0;
        for (;;) {
          kk = __hip_atomic_load(sl, __ATOMIC_RELAXED, __HIP_MEMORY_SCOPE_AGENT);
          if (kk) break;
          if (++r > 256) {                  // slow path: coherence insurance
            kk = atomicMax(sl, 0ull);
            if (kk) break;
            if (__builtin_amdgcn_s_memrealtime() - t0 > 2000000ull) {
              kk = 0xFFFFFFFFull;           // dist 0: loses to any real key
              break;
            }
            __builtin_amdgcn_s_sleep(1);
          }
        }
      }
#pragma unroll
      for (int off = 1; off < FPS_W; off <<= 1) {
        unsigned long long o = __shfl_xor(kk, off, FPS_W);
        if (o > kk) kk = o;
      }
      if (lane == 0) s_win = kk;
    }
    __syncthreads();
    unsigned long long k = s_win;
    int last = (int)((0xFFFFFFFFu - (unsigned)k) & 16383u);
    const float* q = px + (size_t)last * 3;  // broadcast L2 load
    qx = q[0]; qy = q[1]; qz = q[2];
    if (w == 0 && tid == 0) {
      float* o = new_xyz + ((size_t)b * S + it) * 3;
      o[0] = qx; o[1] = qy; o[2] = qz;
    }
  }
}

// ---------------------------------------------------------------------------
// FPS, layers 1-3: T=N<=1024, one point per thread (regs) + coords mirrored
// in LDS for the winner lookup (no global reads in the loop). Fused 64-bit
// reduce. (Verified in rounds 3-4.)
__global__ void fps_small_kernel(const float* __restrict__ xyz,
    float* __restrict__ new_xyz, int N, int S) {
  const int b = blockIdx.x;
  const int tid = threadIdx.x;
  const int lane = tid & 63;
  const float* px = xyz + (size_t)b * N * 3;
  __shared__ float sx[1024], sy[1024], sz[1024];
  __shared__ unsigned long long s_key[3];
  float x = px[tid * 3 + 0], y = px[tid * 3 + 1], z = px[tid * 3 + 2];
  sx[tid] = x; sy[tid] = y; sz[tid] = z;
  if (tid < 3) s_key[tid] = 0ull;
  float mind = 1e10f;
  float qx = px[0], qy = px[1], qz = px[2];
  if (tid == 0) {
    float* o = new_xyz + (size_t)b * S * 3;
    o[0] = qx; o[1] = qy; o[2] = qz;
  }
  __syncthreads();
  for (unsigned it = 1; it < (unsigned)S; ++it) {
    float dx = __fsub_rn(x, qx);
    float dy = __fsub_rn(y, qy);
    float dz = __fsub_rn(z, qz);
    float d = __fadd_rn(__fadd_rn(__fmul_rn(dx, dx), __fmul_rn(dy, dy)), __fmul_rn(dz, dz));
    mind = fminf(mind, d);
    unsigned long long key = ((unsigned long long)__float_as_uint(mind) << 32)
                           | (0xFFFFFFFFu - (unsigned)tid);
    key = dpp_max_u64(key);
    if (lane == 63) atomicMax(&s_key[it % 3u], key);
    if (tid == 0) s_key[(it + 1) % 3u] = 0ull;
    __syncthreads();
    unsigned long long k = s_key[it % 3u];
    int last = (int)(0xFFFFFFFFu - (unsigned)k);
    qx = sx[last]; qy = sy[last]; qz = sz[last];   // LDS broadcast
    if (tid == 0) {
      float* o = new_xyz + ((size_t)b * S + it) * 3;
      o[0] = qx; o[1] = qy; o[2] = qz;
    }
  }
}

// ---------------------------------------------------------------------------
// Ball query: one wave per center; take the FIRST nsample indices (ascending)
// with d2 < r2 (== nsample smallest indices, matching top_k(-key)). Pad with
// the first hit (0 if no hits).
__global__ __launch_bounds__(256) void ballquery_kernel(const float* __restrict__ xyz,
    const float* __restrict__ centers, int* __restrict__ out_idx,
    int N, int S, int nsample, float r2) {
  int gw = (blockIdx.x * blockDim.x + threadIdx.x) >> 6;
  int lane = threadIdx.x & 63;
  int b = gw / S;
  int s = gw - b * S;
  const float* px = xyz + (size_t)b * N * 3;
  const float* cp = centers + ((size_t)b * S + s) * 3;
  float cx = cp[0], cy = cp[1], cz = cp[2];
  int* out = out_idx + ((size_t)b * S + s) * nsample;
  int cnt = 0;
  int firsti = 0;
  for (int base = 0; base < N; base += WAVE) {
    int i = base + lane;
    float dx = __fsub_rn(cx, px[i * 3 + 0]);
    float dy = __fsub_rn(cy, px[i * 3 + 1]);
    float dz = __fsub_rn(cz, px[i * 3 + 2]);
    float d = __fadd_rn(__fadd_rn(__fmul_rn(dx, dx), __fmul_rn(dy, dy)), __fmul_rn(dz, dz));
    bool hit = d < r2;
    unsigned long long m = __ballot(hit);
    if (hit) {
      int slot = cnt + __popcll(m & ((1ull << lane) - 1ull));
      if (slot < nsample) out[slot] = i;
    }
    if (cnt == 0 && m) firsti = base + __ffsll((unsigned long long)m) - 1;
    cnt += __popcll(m);
    if (cnt >= nsample) break;
  }
  for (int q = cnt + lane; q < nsample; q += WAVE) out[q] = firsti;
}

// ---------------------------------------------------------------------------
// Build X0 rows: [xyz[j]-center (3), feats[j] (ci)] for r=(b,s,k), c in [0,3+ci)
__global__ __launch_bounds__(256) void group_kernel(const float* __restrict__ xyz,
    const float* __restrict__ feats, const float* __restrict__ centers,
    const int* __restrict__ idx, float* __restrict__ X,
    int N, int S, int K, int ci, int R) {
  int t = blockIdx.x * blockDim.x + threadIdx.x;
  int C0 = ci + 3;
  int r = t / C0;
  if (r >= R) return;
  int c = t - r * C0;
  int g = r / K;          // b*S + s
  int b = g / S;
  int j = idx[r];
  float v;
  if (c < 3) v = __fsub_rn(xyz[((size_t)b * N + j) * 3 + c], centers[(size_t)g * 3 + c]);
  else       v = feats[((size_t)b * N + j) * ci + (c - 3)];
  X[(size_t)r * C0 + c] = v;
}

// ---------------------------------------------------------------------------
// Fused tiled f32 GEMM: Y(RxCo) = normReLU(A)(RxC) @ W(CxCo).
//  - if st_in != nullptr, A is normalized elementwise during LDS staging:
//      v = relu(gamma_in[c]*((a - mu[c])*rs[c]) + beta_in[c])
//    with mu/rs from st_in (prev sub-layer's sums; complete by stream order).
//  - per-channel sum/sumsq of Y accumulated into st_out (epilogue atomics)
//    -> replaces the separate stats pass.
// R % 64 == 0 always; C/Co guarded.
#define BM 64
#define BN 64
#define BK 16
__global__ __launch_bounds__(256) void mm_fused_kernel(const float* __restrict__ A,
    const float* __restrict__ W, float* __restrict__ Y,
    float* __restrict__ st_out, const float* __restrict__ st_in,
    const float* __restrict__ g_in, const float* __restrict__ b_in,
    int R, int C, int Co, float inv_n) {
  __shared__ float As[BK][BM + 4];
  __shared__ float Bs[BK][BN + 4];
  __shared__ float s_mu[260], s_rs[260], s_g[260], s_b[260];
  __shared__ float s_sum[BN], s_sq[BN];
  int r0 = blockIdx.x * BM;
  int n0 = blockIdx.y * BN;
  int tid = threadIdx.x;
  int tx = tid & 15, ty = tid >> 4;
  if (st_in) {
    for (int c = tid; c < C; c += 256) {
      float mu = st_in[c] * inv_n;
      float var = st_in[512 + c] * inv_n - mu * mu;
      s_mu[c] = mu; s_rs[c] = rsqrtf(var + 1e-5f);
      s_g[c] = g_in[c]; s_b[c] = b_in[c];
    }
  }
  if (tid < BN) { s_sum[tid] = 0.f; s_sq[tid] = 0.f; }
  __syncthreads();
  float acc[4][4] = {};
  for (int k0 = 0; k0 < C; k0 += BK) {
#pragma unroll
    for (int u = 0; u < 4; ++u) {
      int lin = tid + u * 256;
      int row = lin >> 4;
      int cc = lin & 15;
      int c = k0 + cc;
      float v = 0.f;
      if (c < C) {
        v = A[(size_t)(r0 + row) * C + c];
        if (st_in) {
          v = s_g[c] * ((v - s_mu[c]) * s_rs[c]) + s_b[c];
          v = v > 0.f ? v : 0.f;
        }
      }
      As[cc][row] = v;
    }
#pragma unroll
    for (int u = 0; u < 4; ++u) {
      int lin = tid + u * 256;
      int kk = lin >> 6;
      int n = lin & 63;
      int c = k0 + kk;
      Bs[kk][n] = (c < C && (n0 + n) < Co) ? W[(size_t)c * Co + n0 + n] : 0.f;
    }
    __syncthreads();
#pragma unroll
    for (int kk = 0; kk < BK; ++kk) {
      float a0[4], b0[4];
#pragma unroll
      for (int i = 0; i < 4; ++i) a0[i] = As[kk][ty * 4 + i];
#pragma unroll
      for (int jj = 0; jj < 4; ++jj) b0[jj] = Bs[kk][tx * 4 + jj];
#pragma unroll
      for (int i = 0; i < 4; ++i)
#pragma unroll
        for (int jj = 0; jj < 4; ++jj)
          acc[i][jj] = fmaf(a0[i], b0[jj], acc[i][jj]);
    }
    __syncthreads();
  }
#pragma unroll
  for (int i = 0; i < 4; ++i) {
    int r = r0 + ty * 4 + i;
#pragma unroll
    for (int jj = 0; jj < 4; ++jj) {
      int n = n0 + tx * 4 + jj;
      if (n < Co) Y[(size_t)r * Co + n] = acc[i][jj];
    }
  }
  // epilogue: per-column sum/sumsq of this block's tile -> LDS -> global
#pragma unroll
  for (int jj = 0; jj < 4; ++jj) {
    float cs = 0.f, cq = 0.f;
#pragma unroll
    for (int i = 0; i < 4; ++i) { float v = acc[i][jj]; cs += v; cq += v * v; }
    atomicAdd(&s_sum[tx * 4 + jj], cs);
    atomicAdd(&s_sq[tx * 4 + jj], cq);
  }
  __syncthreads();
  if (tid < BN) {
    int n = n0 + tid;
    if (n < Co) {
      atomicAdd(&st_out[n], s_sum[tid]);
      atomicAdd(&st_out[512 + n], s_sq[tid]);
    }
  }
}

// Last sub-layer: normalize+relu then max over the K samples of each group.
__global__ __launch_bounds__(256) void norm_relu_max_kernel(const float* __restrict__ Y,
    float* __restrict__ O, const float* __restrict__ st,
    const float* __restrict__ gamma, const float* __restrict__ beta,
    int G, int K, int Co, float inv_n) {
  int t = blockIdx.x * blockDim.x + threadIdx.x;
  if (t >= G * Co) return;
  int c = t & (Co - 1);
  int g = t / Co;
  float mu = st[c] * inv_n;
  float var = st[512 + c] * inv_n - mu * mu;
  float rs = rsqrtf(var + 1e-5f);
  float ga = gamma[c], be = beta[c];
  const float* yp = Y + (size_t)g * K * Co + c;
  float m = -1e30f;
  for (int k = 0; k < K; ++k) {
    float v = ga * ((yp[(size_t)k * Co] - mu) * rs) + be;
    m = fmaxf(m, v);
  }
  O[t] = m > 0.f ? m : 0.f;
}

// ---------------------------------------------------------------------------
extern "C" void kernel_launch(void* const* d_in, const int* in_sizes, int n_in,
                              void* d_out, int out_size, void* d_ws, size_t ws_size,
                              hipStream_t stream) {
  const float* pc = (const float*)d_in[0];
  float* out = (float*)d_out;
  char* wsb = (char*)d_ws;

  // ws layout: [0,1MB) ball idx; [1MB,+48KB) stats; [2MB,+512KB) fps slots;
  //            [3MB,37MB) bufA; [37MB,104MB) bufB
  int* ballidx = (int*)wsb;
  float* stats = (float*)(wsb + ((size_t)1 << 20));
  unsigned long long* gkey = (unsigned long long*)(wsb + ((size_t)2 << 20));
  float* bufA = (float*)(wsb + ((size_t)3 << 20));
  float* bufB = (float*)(wsb + ((size_t)37 << 20));

  const int B = 8;
  static const int Ns[4] = {16384, 1024, 256, 64};
  static const int Ss[4] = {1024, 256, 64, 16};
  static const int Ks[4] = {32, 32, 16, 16};
  static const double Rr[4] = {0.02, 0.04, 0.06, 0.08};
  static const int Ci[4] = {3, 64, 128, 256};
  static const int mlp[4][4] = {{6,32,32,64},{67,64,64,128},{131,128,128,256},{259,256,256,512}};
  static const size_t ox[5] = {0, 393216, 417792, 423936, 425472};
  static const size_t of[5] = {425856, 819072, 1343360, 1605504, 1736576};

  split_kernel<<<(B * 16384 + 255) / 256, 256, 0, stream>>>(pc, out + ox[0], out + of[0], B * 16384);
  // zero stats (48KB @ +1MB) and fps slots (512KB @ +2MB) in one pass over [1MB,3MB)
  zero_kernel<<<(524288 + 255) / 256, 256, 0, stream>>>(stats, 524288);

  for (int l = 0; l < 4; ++l) {
    const float* xyz = out + ox[l];
    const float* fts = out + of[l];
    float* nxyz = out + ox[l + 1];
    const int N = Ns[l], S = Ss[l], K = Ks[l], ci = Ci[l], C0 = ci + 3;
    const float r2 = (float)(Rr[l] * Rr[l]);

    if (l == 0) fps_big_multi_kernel<<<B * FPS_W, 256, 0, stream>>>(xyz, nxyz, gkey, N, S);
    else        fps_small_kernel<<<B, N, 0, stream>>>(xyz, nxyz, N, S);

    ballquery_kernel<<<(B * S) / 4, 256, 0, stream>>>(xyz, nxyz, ballidx, N, S, K, r2);

    const int R = B * S * K;
    {
      int total = R * C0;
      group_kernel<<<(total + 255) / 256, 256, 0, stream>>>(xyz, fts, nxyz, ballidx, bufA,
                                                            N, S, K, ci, R);
    }

    const float inv_n = 1.0f / (float)R;
    float* X = bufA; float* Y = bufB;
    const float* prev_st = nullptr;
    const float* prev_g = nullptr;
    const float* prev_b = nullptr;
    for (int j = 0; j < 3; ++j) {
      const int cin = mlp[l][j], cout = mlp[l][j + 1];
      const float* Wt = (const float*)d_in[1 + (l * 3 + j) * 3 + 0];
      const float* Ga = (const float*)d_in[1 + (l * 3 + j) * 3 + 1];
      const float* Be = (const float*)d_in[1 + (l * 3 + j) * 3 + 2];
      float* st = stats + (size_t)(l * 3 + j) * 1024;
      dim3 grid(R / 64, (cout + 63) / 64);
      mm_fused_kernel<<<grid, 256, 0, stream>>>(X, Wt, Y, st, prev_st, prev_g, prev_b,
                                                R, cin, cout, inv_n);
      if (j < 2) {
        prev_st = st; prev_g = Ga; prev_b = Be;
        float* tswap = X; X = Y; Y = tswap;
      } else {
        int G = B * S;
        int tot = G * cout;
        norm_relu_max_kernel<<<(tot + 255) / 256, 256, 0, stream>>>(Y, out + of[l + 1], st, Ga, Be,
                                                                    G, K, cout, inv_n);
      }
    }
  }
}